// Round 1
// baseline (2273.263 us; speedup 1.0000x reference)
//
#include <hip/hip_runtime.h>
#include <cstddef>

#define NN 4096
#define UF 128
#define NE 131072

// ---------- edge dtype handling (int64 vs int32 storage) ----------
__device__ __forceinline__ int edge_at(const void* ei, int is64, int idx) {
  if (is64) return (int)((const long long*)ei)[idx];
  return ((const int*)ei)[idx];
}

__global__ void k_init(int* __restrict__ flag, int* __restrict__ deg) {
  int t = blockIdx.x * blockDim.x + threadIdx.x;
  if (t == 0) flag[0] = 1;  // assume int64 until disproven
  if (t < NN) deg[t] = 0;
}

// Read first NE elements as int64: covers exactly the whole buffer if storage
// is int32 (NE*8 == 2*NE*4 bytes), and the src row if storage is int64.
// int32 storage -> pairs combine into huge values -> flag := 0.
__global__ void k_detect(const long long* __restrict__ ei64, int* __restrict__ flag) {
  int t = blockIdx.x * blockDim.x + threadIdx.x;
  if (t >= NE) return;
  long long v = ei64[t];
  if (v < 0 || v >= NN) atomicAnd(flag, 0);
}

// ---------- CSR build ----------
__global__ void k_count(const void* __restrict__ ei, const int* __restrict__ flag,
                        int* __restrict__ deg) {
  int e = blockIdx.x * blockDim.x + threadIdx.x;
  if (e >= NE) return;
  int is64 = flag[0];
  int d = edge_at(ei, is64, NE + e);
  atomicAdd(&deg[d], 1);
}

__global__ __launch_bounds__(1024) void k_scan(const int* __restrict__ deg,
                                               int* __restrict__ rowstart,
                                               int* __restrict__ cursor) {
  __shared__ int part[1024];
  const int t = threadIdx.x;
  int v0 = deg[t*4+0], v1 = deg[t*4+1], v2 = deg[t*4+2], v3 = deg[t*4+3];
  part[t] = v0 + v1 + v2 + v3;
  __syncthreads();
  for (int off = 1; off < 1024; off <<= 1) {
    int add = (t >= off) ? part[t - off] : 0;
    __syncthreads();
    part[t] += add;
    __syncthreads();
  }
  int base = (t == 0) ? 0 : part[t-1];
  int r0 = base, r1 = r0 + v0, r2 = r1 + v1, r3 = r2 + v2;
  rowstart[t*4+0] = r0; rowstart[t*4+1] = r1;
  rowstart[t*4+2] = r2; rowstart[t*4+3] = r3;
  cursor[t*4+0] = r0; cursor[t*4+1] = r1;
  cursor[t*4+2] = r2; cursor[t*4+3] = r3;
  if (t == 1023) rowstart[NN] = part[1023];
}

__global__ void k_scatter(const void* __restrict__ ei, const int* __restrict__ flag,
                          int* __restrict__ cursor, int* __restrict__ csr) {
  int e = blockIdx.x * blockDim.x + threadIdx.x;
  if (e >= NE) return;
  int is64 = flag[0];
  int s = edge_at(ei, is64, e);
  int d = edge_at(ei, is64, NE + e);
  int pos = atomicAdd(&cursor[d], 1);
  csr[pos] = s;
}

// ---------- mean aggregation: one wave per node ----------
__global__ __launch_bounds__(256) void k_aggregate(
    const float* __restrict__ x, const int* __restrict__ rowstart,
    const int* __restrict__ csr, float* __restrict__ agg) {
  int wid = (blockIdx.x * blockDim.x + threadIdx.x) >> 6;
  int lane = threadIdx.x & 63;
  if (wid >= NN) return;
  int s0 = rowstart[wid], s1 = rowstart[wid + 1];
  float f0 = 0.f, f1 = 0.f;
  for (int e = s0; e < s1; ++e) {
    int s = csr[e];
    const float* row = x + (size_t)s * UF;
    f0 += row[lane];
    f1 += row[lane + 64];
  }
  float inv = 1.0f / (float)max(s1 - s0, 1);
  agg[(size_t)wid * UF + lane]      = f0 * inv;
  agg[(size_t)wid * UF + 64 + lane] = f1 * inv;
}

// ---------- SAGE layer: out = agg@Wl^T + bl + in@Wr^T (opt tanh) ----------
// 256 blocks x 256 threads; tile = 16 nodes x 128 outs; thread = 2n x 4o.
template<bool TANH>
__global__ __launch_bounds__(256) void k_layer(
    const float* __restrict__ agg, const float* __restrict__ in,
    const float* __restrict__ Wl, const float* __restrict__ bl,
    const float* __restrict__ Wr, float* __restrict__ out) {
  __shared__ float As[16][132];
  __shared__ float Bs[16][132];
  const int t = threadIdx.x;
  const int base = blockIdx.x * 16;
  for (int idx = t; idx < 512; idx += 256) {
    int row = idx >> 5, c = (idx & 31) * 4;
    *(float4*)&As[row][c] = *(const float4*)(agg + (size_t)(base + row) * UF + c);
    *(float4*)&Bs[row][c] = *(const float4*)(in  + (size_t)(base + row) * UF + c);
  }
  __syncthreads();
  const int o0 = (t & 31) * 4;
  const int n0 = (t >> 5) * 2;
  float acc[2][4] = {};
#pragma unroll
  for (int k = 0; k < UF; k += 4) {
    float4 a[2], w[4];
    a[0] = *(const float4*)&As[n0][k];
    a[1] = *(const float4*)&As[n0 + 1][k];
#pragma unroll
    for (int j = 0; j < 4; ++j) w[j] = *(const float4*)(Wl + (size_t)(o0 + j) * UF + k);
#pragma unroll
    for (int i = 0; i < 2; ++i)
#pragma unroll
      for (int j = 0; j < 4; ++j) {
        acc[i][j] = fmaf(a[i].x, w[j].x, acc[i][j]);
        acc[i][j] = fmaf(a[i].y, w[j].y, acc[i][j]);
        acc[i][j] = fmaf(a[i].z, w[j].z, acc[i][j]);
        acc[i][j] = fmaf(a[i].w, w[j].w, acc[i][j]);
      }
  }
#pragma unroll
  for (int k = 0; k < UF; k += 4) {
    float4 a[2], w[4];
    a[0] = *(const float4*)&Bs[n0][k];
    a[1] = *(const float4*)&Bs[n0 + 1][k];
#pragma unroll
    for (int j = 0; j < 4; ++j) w[j] = *(const float4*)(Wr + (size_t)(o0 + j) * UF + k);
#pragma unroll
    for (int i = 0; i < 2; ++i)
#pragma unroll
      for (int j = 0; j < 4; ++j) {
        acc[i][j] = fmaf(a[i].x, w[j].x, acc[i][j]);
        acc[i][j] = fmaf(a[i].y, w[j].y, acc[i][j]);
        acc[i][j] = fmaf(a[i].z, w[j].z, acc[i][j]);
        acc[i][j] = fmaf(a[i].w, w[j].w, acc[i][j]);
      }
  }
#pragma unroll
  for (int i = 0; i < 2; ++i) {
    float4 r;
    r.x = acc[i][0] + bl[o0 + 0];
    r.y = acc[i][1] + bl[o0 + 1];
    r.z = acc[i][2] + bl[o0 + 2];
    r.w = acc[i][3] + bl[o0 + 3];
    if (TANH) { r.x = tanhf(r.x); r.y = tanhf(r.y); r.z = tanhf(r.z); r.w = tanhf(r.w); }
    *(float4*)(out + (size_t)(base + n0 + i) * UF + o0) = r;
  }
}

// ---------- fused actor+critic heads: x_actor/x_critic stay in registers ----------
__global__ __launch_bounds__(256) void k_heads(
    const float* __restrict__ agg, const float* __restrict__ in,
    const float* __restrict__ Wa_l, const float* __restrict__ ba_l,
    const float* __restrict__ Wa_r,
    const float* __restrict__ Wcr_l, const float* __restrict__ bcr_l,
    const float* __restrict__ Wcr_r,
    const float* __restrict__ Wfa, const float* __restrict__ Wfc,
    float* __restrict__ a1, float* __restrict__ a2, float* __restrict__ cp) {
  __shared__ float As[16][132];
  __shared__ float Bs[16][132];
  __shared__ float red[3][16][33];
  const int t = threadIdx.x;
  const int base = blockIdx.x * 16;
  for (int idx = t; idx < 512; idx += 256) {
    int row = idx >> 5, c = (idx & 31) * 4;
    *(float4*)&As[row][c] = *(const float4*)(agg + (size_t)(base + row) * UF + c);
    *(float4*)&Bs[row][c] = *(const float4*)(in  + (size_t)(base + row) * UF + c);
  }
  __syncthreads();
  const int og = t & 31;
  const int o0 = og * 4;
  const int n0 = (t >> 5) * 2;
  float accA[2][4] = {};
  float accC[2][4] = {};
#pragma unroll
  for (int k = 0; k < UF; k += 4) {
    float4 a[2], wa[4], wc[4];
    a[0] = *(const float4*)&As[n0][k];
    a[1] = *(const float4*)&As[n0 + 1][k];
#pragma unroll
    for (int j = 0; j < 4; ++j) {
      wa[j] = *(const float4*)(Wa_l  + (size_t)(o0 + j) * UF + k);
      wc[j] = *(const float4*)(Wcr_l + (size_t)(o0 + j) * UF + k);
    }
#pragma unroll
    for (int i = 0; i < 2; ++i)
#pragma unroll
      for (int j = 0; j < 4; ++j) {
        accA[i][j] = fmaf(a[i].x, wa[j].x, accA[i][j]);
        accA[i][j] = fmaf(a[i].y, wa[j].y, accA[i][j]);
        accA[i][j] = fmaf(a[i].z, wa[j].z, accA[i][j]);
        accA[i][j] = fmaf(a[i].w, wa[j].w, accA[i][j]);
        accC[i][j] = fmaf(a[i].x, wc[j].x, accC[i][j]);
        accC[i][j] = fmaf(a[i].y, wc[j].y, accC[i][j]);
        accC[i][j] = fmaf(a[i].z, wc[j].z, accC[i][j]);
        accC[i][j] = fmaf(a[i].w, wc[j].w, accC[i][j]);
      }
  }
#pragma unroll
  for (int k = 0; k < UF; k += 4) {
    float4 a[2], wa[4], wc[4];
    a[0] = *(const float4*)&Bs[n0][k];
    a[1] = *(const float4*)&Bs[n0 + 1][k];
#pragma unroll
    for (int j = 0; j < 4; ++j) {
      wa[j] = *(const float4*)(Wa_r  + (size_t)(o0 + j) * UF + k);
      wc[j] = *(const float4*)(Wcr_r + (size_t)(o0 + j) * UF + k);
    }
#pragma unroll
    for (int i = 0; i < 2; ++i)
#pragma unroll
      for (int j = 0; j < 4; ++j) {
        accA[i][j] = fmaf(a[i].x, wa[j].x, accA[i][j]);
        accA[i][j] = fmaf(a[i].y, wa[j].y, accA[i][j]);
        accA[i][j] = fmaf(a[i].z, wa[j].z, accA[i][j]);
        accA[i][j] = fmaf(a[i].w, wa[j].w, accA[i][j]);
        accC[i][j] = fmaf(a[i].x, wc[j].x, accC[i][j]);
        accC[i][j] = fmaf(a[i].y, wc[j].y, accC[i][j]);
        accC[i][j] = fmaf(a[i].z, wc[j].z, accC[i][j]);
        accC[i][j] = fmaf(a[i].w, wc[j].w, accC[i][j]);
      }
  }
  // add biases, project to a1/a2/cp partials
#pragma unroll
  for (int i = 0; i < 2; ++i) {
    float pa1 = 0.f, pa2 = 0.f, pc = 0.f;
#pragma unroll
    for (int j = 0; j < 4; ++j) {
      float xa = accA[i][j] + ba_l[o0 + j];
      float xc = accC[i][j] + bcr_l[o0 + j];
      pa1 = fmaf(xa, Wfa[o0 + j], pa1);
      pa2 = fmaf(xa, Wfa[UF + o0 + j], pa2);
      pc  = fmaf(xc, Wfc[o0 + j], pc);
    }
    red[0][n0 + i][og] = pa1;
    red[1][n0 + i][og] = pa2;
    red[2][n0 + i][og] = pc;
  }
  __syncthreads();
  if (t < 48) {
    int q = t >> 4, n = t & 15;
    float s = 0.f;
#pragma unroll
    for (int j = 0; j < 32; ++j) s += red[q][n][j];
    float* dst = (q == 0) ? a1 : (q == 1) ? a2 : cp;
    dst[base + n] = s;
  }
}

// ---------- global reductions: LSE constant + critic scalar ----------
__global__ __launch_bounds__(1024) void k_reduce(
    const float* __restrict__ a1, const float* __restrict__ a2,
    const float* __restrict__ cp, const float* __restrict__ bfc,
    float* __restrict__ consts, float* __restrict__ outc) {
  __shared__ float sm[1024];
  const int t = threadIdx.x;
  float x0 = a1[t*4], x1 = a1[t*4+1], x2 = a1[t*4+2], x3 = a1[t*4+3];
  float y0 = a2[t*4], y1 = a2[t*4+1], y2 = a2[t*4+2], y3 = a2[t*4+3];
  float c0 = cp[t*4], c1 = cp[t*4+1], c2 = cp[t*4+2], c3 = cp[t*4+3];

  sm[t] = fmaxf(fmaxf(x0, x1), fmaxf(x2, x3));
  __syncthreads();
  for (int off = 512; off > 0; off >>= 1) { if (t < off) sm[t] = fmaxf(sm[t], sm[t+off]); __syncthreads(); }
  float m1 = sm[0]; __syncthreads();

  sm[t] = fmaxf(fmaxf(y0, y1), fmaxf(y2, y3));
  __syncthreads();
  for (int off = 512; off > 0; off >>= 1) { if (t < off) sm[t] = fmaxf(sm[t], sm[t+off]); __syncthreads(); }
  float m2 = sm[0]; __syncthreads();

  sm[t] = expf(x0-m1) + expf(x1-m1) + expf(x2-m1) + expf(x3-m1);
  __syncthreads();
  for (int off = 512; off > 0; off >>= 1) { if (t < off) sm[t] += sm[t+off]; __syncthreads(); }
  float s1 = sm[0]; __syncthreads();

  sm[t] = expf(y0-m2) + expf(y1-m2) + expf(y2-m2) + expf(y3-m2);
  __syncthreads();
  for (int off = 512; off > 0; off >>= 1) { if (t < off) sm[t] += sm[t+off]; __syncthreads(); }
  float s2 = sm[0]; __syncthreads();

  sm[t] = c0 + c1 + c2 + c3;
  __syncthreads();
  for (int off = 512; off > 0; off >>= 1) { if (t < off) sm[t] += sm[t+off]; __syncthreads(); }
  float sc = sm[0];

  if (t == 0) {
    // edge_actor[i,j] = a1[i]+a2[j]+bfa - (m1+m2+bfa+log(s1*s2))
    consts[0] = -(m1 + m2 + logf(s1) + logf(s2));
    outc[0] = tanhf(sc * (1.0f / (float)NN) + bfc[0]);
  }
}

// ---------- N^2 output write ----------
__global__ __launch_bounds__(256) void k_write(
    const float* __restrict__ a1, const float* __restrict__ a2,
    const float* __restrict__ consts, float* __restrict__ out) {
  int gid = blockIdx.x * 256 + threadIdx.x;        // one float4 per thread
  int row = gid >> 10;                             // 1024 float4 per row
  int c = (gid & 1023) * 4;
  float C = consts[0] + a1[row];
  float4 v = *(const float4*)(a2 + c);
  float4 r; r.x = v.x + C; r.y = v.y + C; r.z = v.z + C; r.w = v.w + C;
  *(float4*)(out + (size_t)gid * 4) = r;
}

extern "C" void kernel_launch(void* const* d_in, const int* in_sizes, int n_in,
                              void* d_out, int out_size, void* d_ws, size_t ws_size,
                              hipStream_t stream) {
  const float* x     = (const float*)d_in[0];
  const void*  ei    = d_in[1];
  const float* Wf_l  = (const float*)d_in[3];
  const float* bf_l  = (const float*)d_in[4];
  const float* Wf_r  = (const float*)d_in[5];
  const float* Wcm_l = (const float*)d_in[6];
  const float* bcm_l = (const float*)d_in[7];
  const float* Wcm_r = (const float*)d_in[8];
  const float* Wa_l  = (const float*)d_in[9];
  const float* ba_l  = (const float*)d_in[10];
  const float* Wa_r  = (const float*)d_in[11];
  const float* Wcr_l = (const float*)d_in[12];
  const float* bcr_l = (const float*)d_in[13];
  const float* Wcr_r = (const float*)d_in[14];
  const float* Wfa   = (const float*)d_in[15];
  const float* Wfc   = (const float*)d_in[17];
  const float* bfc   = (const float*)d_in[18];
  float* out = (float*)d_out;

  char* b = (char*)d_ws;
  size_t off = 0;
  int* flag = (int*)(b + off); off += 256;
  float* consts = (float*)(b + off); off += 256;
  int* deg = (int*)(b + off); off += (size_t)NN * 4;
  int* rowstart = (int*)(b + off); off += (size_t)(NN + 64) * 4;
  int* cursor = (int*)(b + off); off += (size_t)NN * 4;
  int* csr = (int*)(b + off); off += (size_t)NE * 4;
  float* a1 = (float*)(b + off); off += (size_t)NN * 4;
  float* a2 = (float*)(b + off); off += (size_t)NN * 4;
  float* cp = (float*)(b + off); off += (size_t)NN * 4;
  float* agg = (float*)(b + off); off += (size_t)NN * UF * 4;
  float* h1 = (float*)(b + off); off += (size_t)NN * UF * 4;
  float* h2 = (float*)(b + off); off += (size_t)NN * UF * 4;
  if (ws_size < off) return;

  k_init<<<16, 256, 0, stream>>>(flag, deg);
  k_detect<<<NE / 256, 256, 0, stream>>>((const long long*)ei, flag);
  k_count<<<NE / 256, 256, 0, stream>>>(ei, flag, deg);
  k_scan<<<1, 1024, 0, stream>>>(deg, rowstart, cursor);
  k_scatter<<<NE / 256, 256, 0, stream>>>(ei, flag, cursor, csr);

  k_aggregate<<<NN / 4, 256, 0, stream>>>(x, rowstart, csr, agg);
  k_layer<true><<<NN / 16, 256, 0, stream>>>(agg, x, Wf_l, bf_l, Wf_r, h1);
  k_aggregate<<<NN / 4, 256, 0, stream>>>(h1, rowstart, csr, agg);
  k_layer<true><<<NN / 16, 256, 0, stream>>>(agg, h1, Wcm_l, bcm_l, Wcm_r, h2);
  k_aggregate<<<NN / 4, 256, 0, stream>>>(h2, rowstart, csr, agg);
  k_heads<<<NN / 16, 256, 0, stream>>>(agg, h2, Wa_l, ba_l, Wa_r,
                                       Wcr_l, bcr_l, Wcr_r, Wfa, Wfc, a1, a2, cp);
  k_reduce<<<1, 1024, 0, stream>>>(a1, a2, cp, bfc, consts, out + (size_t)NN * NN);
  k_write<<<(NN * NN) / 1024, 256, 0, stream>>>(a1, a2, consts, out);
}

// Round 2
// 761.019 us; speedup vs baseline: 2.9871x; 2.9871x over previous
//
#include <hip/hip_runtime.h>
#include <cstddef>

#define NN 4096
#define UF 128
#define NE 131072

// ---------- edge dtype handling (int64 vs int32 storage) ----------
__device__ __forceinline__ int edge_at(const void* ei, int is64, int idx) {
  if (is64) return (int)((const long long*)ei)[idx];
  return ((const int*)ei)[idx];
}

__global__ void k_init(int* __restrict__ flag, int* __restrict__ deg) {
  int t = blockIdx.x * blockDim.x + threadIdx.x;
  if (t == 0) flag[0] = 1;  // assume int64 until disproven
  if (t < NN) deg[t] = 0;
}

// Read first NE elements as int64: covers exactly the whole buffer if storage
// is int32 (NE*8 == 2*NE*4 bytes), and the src row if storage is int64.
// int32 storage -> pairs combine into huge values -> flag := 0.
// NO per-thread atomics (previous version: 131k serialized RMWs on one line
// = 1487 us). Wave-ballot + plain store of the same value by lane 0; benign
// race, visibility via dispatch-boundary release (same mechanism as every
// other inter-kernel buffer here).
__global__ void k_detect(const long long* __restrict__ ei64, int* __restrict__ flag) {
  int t = blockIdx.x * blockDim.x + threadIdx.x;
  long long v = ei64[t];
  bool viol = (v < 0 || v >= NN);
  if (__ballot(viol)) {
    if ((threadIdx.x & 63) == 0) flag[0] = 0;
  }
}

// ---------- CSR build ----------
__global__ void k_count(const void* __restrict__ ei, const int* __restrict__ flag,
                        int* __restrict__ deg) {
  int e = blockIdx.x * blockDim.x + threadIdx.x;
  if (e >= NE) return;
  int is64 = flag[0];
  int d = edge_at(ei, is64, NE + e);
  atomicAdd(&deg[d], 1);
}

__global__ __launch_bounds__(1024) void k_scan(const int* __restrict__ deg,
                                               int* __restrict__ rowstart,
                                               int* __restrict__ cursor) {
  __shared__ int part[1024];
  const int t = threadIdx.x;
  int v0 = deg[t*4+0], v1 = deg[t*4+1], v2 = deg[t*4+2], v3 = deg[t*4+3];
  part[t] = v0 + v1 + v2 + v3;
  __syncthreads();
  for (int off = 1; off < 1024; off <<= 1) {
    int add = (t >= off) ? part[t - off] : 0;
    __syncthreads();
    part[t] += add;
    __syncthreads();
  }
  int base = (t == 0) ? 0 : part[t-1];
  int r0 = base, r1 = r0 + v0, r2 = r1 + v1, r3 = r2 + v2;
  rowstart[t*4+0] = r0; rowstart[t*4+1] = r1;
  rowstart[t*4+2] = r2; rowstart[t*4+3] = r3;
  cursor[t*4+0] = r0; cursor[t*4+1] = r1;
  cursor[t*4+2] = r2; cursor[t*4+3] = r3;
  if (t == 1023) rowstart[NN] = part[1023];
}

__global__ void k_scatter(const void* __restrict__ ei, const int* __restrict__ flag,
                          int* __restrict__ cursor, int* __restrict__ csr) {
  int e = blockIdx.x * blockDim.x + threadIdx.x;
  if (e >= NE) return;
  int is64 = flag[0];
  int s = edge_at(ei, is64, e);
  int d = edge_at(ei, is64, NE + e);
  int pos = atomicAdd(&cursor[d], 1);
  csr[pos] = s;
}

// ---------- mean aggregation: one wave per node, float2/lane = 1 row/instr ----------
__global__ __launch_bounds__(256) void k_aggregate(
    const float* __restrict__ x, const int* __restrict__ rowstart,
    const int* __restrict__ csr, float* __restrict__ agg) {
  int wid = (blockIdx.x * blockDim.x + threadIdx.x) >> 6;
  int lane = threadIdx.x & 63;
  if (wid >= NN) return;
  int s0 = rowstart[wid], s1 = rowstart[wid + 1];
  float f0 = 0.f, f1 = 0.f;
#pragma unroll 4
  for (int e = s0; e < s1; ++e) {
    int s = csr[e];
    float2 v = *((const float2*)(x + (size_t)s * UF) + lane);
    f0 += v.x;
    f1 += v.y;
  }
  float inv = 1.0f / (float)max(s1 - s0, 1);
  float2 r; r.x = f0 * inv; r.y = f1 * inv;
  *((float2*)(agg + (size_t)wid * UF) + lane) = r;
}

// ---------- SAGE layer: out = agg@Wl^T + bl + in@Wr^T (opt tanh) ----------
// 256 blocks x 256 threads; tile = 16 nodes x 128 outs; thread = 2n x 4o.
template<bool TANH>
__global__ __launch_bounds__(256) void k_layer(
    const float* __restrict__ agg, const float* __restrict__ in,
    const float* __restrict__ Wl, const float* __restrict__ bl,
    const float* __restrict__ Wr, float* __restrict__ out) {
  __shared__ float As[16][132];
  __shared__ float Bs[16][132];
  const int t = threadIdx.x;
  const int base = blockIdx.x * 16;
  for (int idx = t; idx < 512; idx += 256) {
    int row = idx >> 5, c = (idx & 31) * 4;
    *(float4*)&As[row][c] = *(const float4*)(agg + (size_t)(base + row) * UF + c);
    *(float4*)&Bs[row][c] = *(const float4*)(in  + (size_t)(base + row) * UF + c);
  }
  __syncthreads();
  const int o0 = (t & 31) * 4;
  const int n0 = (t >> 5) * 2;
  float acc[2][4] = {};
#pragma unroll
  for (int k = 0; k < UF; k += 4) {
    float4 a[2], w[4];
    a[0] = *(const float4*)&As[n0][k];
    a[1] = *(const float4*)&As[n0 + 1][k];
#pragma unroll
    for (int j = 0; j < 4; ++j) w[j] = *(const float4*)(Wl + (size_t)(o0 + j) * UF + k);
#pragma unroll
    for (int i = 0; i < 2; ++i)
#pragma unroll
      for (int j = 0; j < 4; ++j) {
        acc[i][j] = fmaf(a[i].x, w[j].x, acc[i][j]);
        acc[i][j] = fmaf(a[i].y, w[j].y, acc[i][j]);
        acc[i][j] = fmaf(a[i].z, w[j].z, acc[i][j]);
        acc[i][j] = fmaf(a[i].w, w[j].w, acc[i][j]);
      }
  }
#pragma unroll
  for (int k = 0; k < UF; k += 4) {
    float4 a[2], w[4];
    a[0] = *(const float4*)&Bs[n0][k];
    a[1] = *(const float4*)&Bs[n0 + 1][k];
#pragma unroll
    for (int j = 0; j < 4; ++j) w[j] = *(const float4*)(Wr + (size_t)(o0 + j) * UF + k);
#pragma unroll
    for (int i = 0; i < 2; ++i)
#pragma unroll
      for (int j = 0; j < 4; ++j) {
        acc[i][j] = fmaf(a[i].x, w[j].x, acc[i][j]);
        acc[i][j] = fmaf(a[i].y, w[j].y, acc[i][j]);
        acc[i][j] = fmaf(a[i].z, w[j].z, acc[i][j]);
        acc[i][j] = fmaf(a[i].w, w[j].w, acc[i][j]);
      }
  }
#pragma unroll
  for (int i = 0; i < 2; ++i) {
    float4 r;
    r.x = acc[i][0] + bl[o0 + 0];
    r.y = acc[i][1] + bl[o0 + 1];
    r.z = acc[i][2] + bl[o0 + 2];
    r.w = acc[i][3] + bl[o0 + 3];
    if (TANH) { r.x = tanhf(r.x); r.y = tanhf(r.y); r.z = tanhf(r.z); r.w = tanhf(r.w); }
    *(float4*)(out + (size_t)(base + n0 + i) * UF + o0) = r;
  }
}

// ---------- fused actor+critic heads: x_actor/x_critic stay in registers ----------
__global__ __launch_bounds__(256) void k_heads(
    const float* __restrict__ agg, const float* __restrict__ in,
    const float* __restrict__ Wa_l, const float* __restrict__ ba_l,
    const float* __restrict__ Wa_r,
    const float* __restrict__ Wcr_l, const float* __restrict__ bcr_l,
    const float* __restrict__ Wcr_r,
    const float* __restrict__ Wfa, const float* __restrict__ Wfc,
    float* __restrict__ a1, float* __restrict__ a2, float* __restrict__ cp) {
  __shared__ float As[16][132];
  __shared__ float Bs[16][132];
  __shared__ float red[3][16][33];
  const int t = threadIdx.x;
  const int base = blockIdx.x * 16;
  for (int idx = t; idx < 512; idx += 256) {
    int row = idx >> 5, c = (idx & 31) * 4;
    *(float4*)&As[row][c] = *(const float4*)(agg + (size_t)(base + row) * UF + c);
    *(float4*)&Bs[row][c] = *(const float4*)(in  + (size_t)(base + row) * UF + c);
  }
  __syncthreads();
  const int og = t & 31;
  const int o0 = og * 4;
  const int n0 = (t >> 5) * 2;
  float accA[2][4] = {};
  float accC[2][4] = {};
#pragma unroll
  for (int k = 0; k < UF; k += 4) {
    float4 a[2], wa[4], wc[4];
    a[0] = *(const float4*)&As[n0][k];
    a[1] = *(const float4*)&As[n0 + 1][k];
#pragma unroll
    for (int j = 0; j < 4; ++j) {
      wa[j] = *(const float4*)(Wa_l  + (size_t)(o0 + j) * UF + k);
      wc[j] = *(const float4*)(Wcr_l + (size_t)(o0 + j) * UF + k);
    }
#pragma unroll
    for (int i = 0; i < 2; ++i)
#pragma unroll
      for (int j = 0; j < 4; ++j) {
        accA[i][j] = fmaf(a[i].x, wa[j].x, accA[i][j]);
        accA[i][j] = fmaf(a[i].y, wa[j].y, accA[i][j]);
        accA[i][j] = fmaf(a[i].z, wa[j].z, accA[i][j]);
        accA[i][j] = fmaf(a[i].w, wa[j].w, accA[i][j]);
        accC[i][j] = fmaf(a[i].x, wc[j].x, accC[i][j]);
        accC[i][j] = fmaf(a[i].y, wc[j].y, accC[i][j]);
        accC[i][j] = fmaf(a[i].z, wc[j].z, accC[i][j]);
        accC[i][j] = fmaf(a[i].w, wc[j].w, accC[i][j]);
      }
  }
#pragma unroll
  for (int k = 0; k < UF; k += 4) {
    float4 a[2], wa[4], wc[4];
    a[0] = *(const float4*)&Bs[n0][k];
    a[1] = *(const float4*)&Bs[n0 + 1][k];
#pragma unroll
    for (int j = 0; j < 4; ++j) {
      wa[j] = *(const float4*)(Wa_r  + (size_t)(o0 + j) * UF + k);
      wc[j] = *(const float4*)(Wcr_r + (size_t)(o0 + j) * UF + k);
    }
#pragma unroll
    for (int i = 0; i < 2; ++i)
#pragma unroll
      for (int j = 0; j < 4; ++j) {
        accA[i][j] = fmaf(a[i].x, wa[j].x, accA[i][j]);
        accA[i][j] = fmaf(a[i].y, wa[j].y, accA[i][j]);
        accA[i][j] = fmaf(a[i].z, wa[j].z, accA[i][j]);
        accA[i][j] = fmaf(a[i].w, wa[j].w, accA[i][j]);
        accC[i][j] = fmaf(a[i].x, wc[j].x, accC[i][j]);
        accC[i][j] = fmaf(a[i].y, wc[j].y, accC[i][j]);
        accC[i][j] = fmaf(a[i].z, wc[j].z, accC[i][j]);
        accC[i][j] = fmaf(a[i].w, wc[j].w, accC[i][j]);
      }
  }
  // add biases, project to a1/a2/cp partials
#pragma unroll
  for (int i = 0; i < 2; ++i) {
    float pa1 = 0.f, pa2 = 0.f, pc = 0.f;
#pragma unroll
    for (int j = 0; j < 4; ++j) {
      float xa = accA[i][j] + ba_l[o0 + j];
      float xc = accC[i][j] + bcr_l[o0 + j];
      pa1 = fmaf(xa, Wfa[o0 + j], pa1);
      pa2 = fmaf(xa, Wfa[UF + o0 + j], pa2);
      pc  = fmaf(xc, Wfc[o0 + j], pc);
    }
    red[0][n0 + i][og] = pa1;
    red[1][n0 + i][og] = pa2;
    red[2][n0 + i][og] = pc;
  }
  __syncthreads();
  if (t < 48) {
    int q = t >> 4, n = t & 15;
    float s = 0.f;
#pragma unroll
    for (int j = 0; j < 32; ++j) s += red[q][n][j];
    float* dst = (q == 0) ? a1 : (q == 1) ? a2 : cp;
    dst[base + n] = s;
  }
}

// ---------- global reductions: LSE constant + critic scalar ----------
__global__ __launch_bounds__(1024) void k_reduce(
    const float* __restrict__ a1, const float* __restrict__ a2,
    const float* __restrict__ cp, const float* __restrict__ bfc,
    float* __restrict__ consts, float* __restrict__ outc) {
  __shared__ float sm[1024];
  const int t = threadIdx.x;
  float x0 = a1[t*4], x1 = a1[t*4+1], x2 = a1[t*4+2], x3 = a1[t*4+3];
  float y0 = a2[t*4], y1 = a2[t*4+1], y2 = a2[t*4+2], y3 = a2[t*4+3];
  float c0 = cp[t*4], c1 = cp[t*4+1], c2 = cp[t*4+2], c3 = cp[t*4+3];

  sm[t] = fmaxf(fmaxf(x0, x1), fmaxf(x2, x3));
  __syncthreads();
  for (int off = 512; off > 0; off >>= 1) { if (t < off) sm[t] = fmaxf(sm[t], sm[t+off]); __syncthreads(); }
  float m1 = sm[0]; __syncthreads();

  sm[t] = fmaxf(fmaxf(y0, y1), fmaxf(y2, y3));
  __syncthreads();
  for (int off = 512; off > 0; off >>= 1) { if (t < off) sm[t] = fmaxf(sm[t], sm[t+off]); __syncthreads(); }
  float m2 = sm[0]; __syncthreads();

  sm[t] = expf(x0-m1) + expf(x1-m1) + expf(x2-m1) + expf(x3-m1);
  __syncthreads();
  for (int off = 512; off > 0; off >>= 1) { if (t < off) sm[t] += sm[t+off]; __syncthreads(); }
  float s1 = sm[0]; __syncthreads();

  sm[t] = expf(y0-m2) + expf(y1-m2) + expf(y2-m2) + expf(y3-m2);
  __syncthreads();
  for (int off = 512; off > 0; off >>= 1) { if (t < off) sm[t] += sm[t+off]; __syncthreads(); }
  float s2 = sm[0]; __syncthreads();

  sm[t] = c0 + c1 + c2 + c3;
  __syncthreads();
  for (int off = 512; off > 0; off >>= 1) { if (t < off) sm[t] += sm[t+off]; __syncthreads(); }
  float sc = sm[0];

  if (t == 0) {
    // edge_actor[i,j] = a1[i]+a2[j]+bfa - (m1+m2+bfa+log(s1*s2))
    consts[0] = -(m1 + m2 + logf(s1) + logf(s2));
    outc[0] = tanhf(sc * (1.0f / (float)NN) + bfc[0]);
  }
}

// ---------- N^2 output write ----------
__global__ __launch_bounds__(256) void k_write(
    const float* __restrict__ a1, const float* __restrict__ a2,
    const float* __restrict__ consts, float* __restrict__ out) {
  int gid = blockIdx.x * 256 + threadIdx.x;        // one float4 per thread
  int row = gid >> 10;                             // 1024 float4 per row
  int c = (gid & 1023) * 4;
  float C = consts[0] + a1[row];
  float4 v = *(const float4*)(a2 + c);
  float4 r; r.x = v.x + C; r.y = v.y + C; r.z = v.z + C; r.w = v.w + C;
  *(float4*)(out + (size_t)gid * 4) = r;
}

extern "C" void kernel_launch(void* const* d_in, const int* in_sizes, int n_in,
                              void* d_out, int out_size, void* d_ws, size_t ws_size,
                              hipStream_t stream) {
  const float* x     = (const float*)d_in[0];
  const void*  ei    = d_in[1];
  const float* Wf_l  = (const float*)d_in[3];
  const float* bf_l  = (const float*)d_in[4];
  const float* Wf_r  = (const float*)d_in[5];
  const float* Wcm_l = (const float*)d_in[6];
  const float* bcm_l = (const float*)d_in[7];
  const float* Wcm_r = (const float*)d_in[8];
  const float* Wa_l  = (const float*)d_in[9];
  const float* ba_l  = (const float*)d_in[10];
  const float* Wa_r  = (const float*)d_in[11];
  const float* Wcr_l = (const float*)d_in[12];
  const float* bcr_l = (const float*)d_in[13];
  const float* Wcr_r = (const float*)d_in[14];
  const float* Wfa   = (const float*)d_in[15];
  const float* Wfc   = (const float*)d_in[17];
  const float* bfc   = (const float*)d_in[18];
  float* out = (float*)d_out;

  char* b = (char*)d_ws;
  size_t off = 0;
  int* flag = (int*)(b + off); off += 256;
  float* consts = (float*)(b + off); off += 256;
  int* deg = (int*)(b + off); off += (size_t)NN * 4;
  int* rowstart = (int*)(b + off); off += (size_t)(NN + 64) * 4;
  int* cursor = (int*)(b + off); off += (size_t)NN * 4;
  int* csr = (int*)(b + off); off += (size_t)NE * 4;
  float* a1 = (float*)(b + off); off += (size_t)NN * 4;
  float* a2 = (float*)(b + off); off += (size_t)NN * 4;
  float* cp = (float*)(b + off); off += (size_t)NN * 4;
  float* agg = (float*)(b + off); off += (size_t)NN * UF * 4;
  float* h1 = (float*)(b + off); off += (size_t)NN * UF * 4;
  float* h2 = (float*)(b + off); off += (size_t)NN * UF * 4;
  if (ws_size < off) return;

  k_init<<<16, 256, 0, stream>>>(flag, deg);
  k_detect<<<NE / 256, 256, 0, stream>>>((const long long*)ei, flag);
  k_count<<<NE / 256, 256, 0, stream>>>(ei, flag, deg);
  k_scan<<<1, 1024, 0, stream>>>(deg, rowstart, cursor);
  k_scatter<<<NE / 256, 256, 0, stream>>>(ei, flag, cursor, csr);

  k_aggregate<<<NN / 4, 256, 0, stream>>>(x, rowstart, csr, agg);
  k_layer<true><<<NN / 16, 256, 0, stream>>>(agg, x, Wf_l, bf_l, Wf_r, h1);
  k_aggregate<<<NN / 4, 256, 0, stream>>>(h1, rowstart, csr, agg);
  k_layer<true><<<NN / 16, 256, 0, stream>>>(agg, h1, Wcm_l, bcm_l, Wcm_r, h2);
  k_aggregate<<<NN / 4, 256, 0, stream>>>(h2, rowstart, csr, agg);
  k_heads<<<NN / 16, 256, 0, stream>>>(agg, h2, Wa_l, ba_l, Wa_r,
                                       Wcr_l, bcr_l, Wcr_r, Wfa, Wfc, a1, a2, cp);
  k_reduce<<<1, 1024, 0, stream>>>(a1, a2, cp, bfc, consts, out + (size_t)NN * NN);
  k_write<<<(NN * NN) / 1024, 256, 0, stream>>>(a1, a2, consts, out);
}

// Round 3
// 144.905 us; speedup vs baseline: 15.6880x; 5.2519x over previous
//
#include <hip/hip_runtime.h>
#include <cstddef>

#define NN 4096
#define UF 128
#define NE 131072

// ---------- edge dtype handling (int64 vs int32 storage) ----------
__device__ __forceinline__ int edge_at(const void* ei, int is64, int idx) {
  if (is64) return (int)((const long long*)ei)[idx];
  return ((const int*)ei)[idx];
}

__global__ void k_init(int* __restrict__ flag, int* __restrict__ deg) {
  int t = blockIdx.x * blockDim.x + threadIdx.x;
  if (t == 0) flag[0] = 1;  // assume int64 until disproven
  if (t < NN) deg[t] = 0;
}

// Wave-ballot + plain store (benign race); NO per-thread atomics.
__global__ void k_detect(const long long* __restrict__ ei64, int* __restrict__ flag) {
  int t = blockIdx.x * blockDim.x + threadIdx.x;
  long long v = ei64[t];
  bool viol = (v < 0 || v >= NN);
  if (__ballot(viol)) {
    if ((threadIdx.x & 63) == 0) flag[0] = 0;
  }
}

// ---------- CSR build ----------
__global__ void k_count(const void* __restrict__ ei, const int* __restrict__ flag,
                        int* __restrict__ deg) {
  int e = blockIdx.x * blockDim.x + threadIdx.x;
  if (e >= NE) return;
  int is64 = flag[0];
  int d = edge_at(ei, is64, NE + e);
  atomicAdd(&deg[d], 1);
}

__global__ __launch_bounds__(1024) void k_scan(const int* __restrict__ deg,
                                               int* __restrict__ rowstart,
                                               int* __restrict__ cursor) {
  __shared__ int part[1024];
  const int t = threadIdx.x;
  int v0 = deg[t*4+0], v1 = deg[t*4+1], v2 = deg[t*4+2], v3 = deg[t*4+3];
  part[t] = v0 + v1 + v2 + v3;
  __syncthreads();
  for (int off = 1; off < 1024; off <<= 1) {
    int add = (t >= off) ? part[t - off] : 0;
    __syncthreads();
    part[t] += add;
    __syncthreads();
  }
  int base = (t == 0) ? 0 : part[t-1];
  int r0 = base, r1 = r0 + v0, r2 = r1 + v1, r3 = r2 + v2;
  rowstart[t*4+0] = r0; rowstart[t*4+1] = r1;
  rowstart[t*4+2] = r2; rowstart[t*4+3] = r3;
  cursor[t*4+0] = r0; cursor[t*4+1] = r1;
  cursor[t*4+2] = r2; cursor[t*4+3] = r3;
  if (t == 1023) rowstart[NN] = part[1023];
}

__global__ void k_scatter(const void* __restrict__ ei, const int* __restrict__ flag,
                          int* __restrict__ cursor, int* __restrict__ csr) {
  int e = blockIdx.x * blockDim.x + threadIdx.x;
  if (e >= NE) return;
  int is64 = flag[0];
  int s = edge_at(ei, is64, e);
  int d = edge_at(ei, is64, NE + e);
  int pos = atomicAdd(&cursor[d], 1);
  csr[pos] = s;
}

// ---------- mean aggregation: one wave per node, float2/lane = 1 row/instr ----------
__global__ __launch_bounds__(256) void k_aggregate(
    const float* __restrict__ x, const int* __restrict__ rowstart,
    const int* __restrict__ csr, float* __restrict__ agg) {
  int wid = (blockIdx.x * blockDim.x + threadIdx.x) >> 6;
  int lane = threadIdx.x & 63;
  if (wid >= NN) return;
  int s0 = rowstart[wid], s1 = rowstart[wid + 1];
  float f0 = 0.f, f1 = 0.f;
#pragma unroll 4
  for (int e = s0; e < s1; ++e) {
    int s = csr[e];
    float2 v = *((const float2*)(x + (size_t)s * UF) + lane);
    f0 += v.x;
    f1 += v.y;
  }
  float inv = 1.0f / (float)max(s1 - s0, 1);
  float2 r; r.x = f0 * inv; r.y = f1 * inv;
  *((float2*)(agg + (size_t)wid * UF) + lane) = r;
}

// ---------- SAGE layer as one K=256 GEMM: A'=[agg|in], W'=[Wl|Wr], LDS-staged ----------
// tile: 16 nodes x 128 outs, 256 threads (thread = 2n x 4o). W' staged in
// K-chunks of 32 (transposed Ws[kk][o]) so the hot loop is pure ds_read+fma
// (previous version: global W loads hoisted by full unroll -> 256 VGPR + 321MB
// scratch spill traffic -> 328us).
template<bool TANH>
__global__ __launch_bounds__(256) void k_layer(
    const float* __restrict__ agg, const float* __restrict__ in,
    const float* __restrict__ Wl, const float* __restrict__ bl,
    const float* __restrict__ Wr, float* __restrict__ out) {
  __shared__ float As[16][260];    // 16 nodes x K=256 (+pad)
  __shared__ float Ws[32][132];    // K-chunk x 128 outs (+pad)
  const int t = threadIdx.x;
  const int base = blockIdx.x * 16;

  // stage A' once: 1024 float4, 4 per thread
#pragma unroll
  for (int r = 0; r < 4; ++r) {
    int idx = t + 256 * r;
    int row = idx >> 6;
    int k = (idx & 63) * 4;
    const float* src = (k < 128) ? (agg + (size_t)(base + row) * UF + k)
                                 : (in  + (size_t)(base + row) * UF + (k - 128));
    *(float4*)&As[row][k] = *(const float4*)src;
  }

  const int o0 = (t & 31) * 4;
  const int n0 = (t >> 5) * 2;
  const int wo = t & 127;          // W-stage: output row handled by this thread
  const int kqb = (t >> 7) * 4;    // W-stage: which 4 of the 8 float4-groups
  float acc[2][4] = {};

  for (int kc = 0; kc < 8; ++kc) {
    __syncthreads();               // Ws reuse guard (no-op on first iter w/ A barrier need anyway)
    // stage W' chunk: Ws[kk][o] = W'[o][kc*32+kk]; 4 float4 per thread
#pragma unroll
    for (int q = 0; q < 4; ++q) {
      int kq = kqb + q;                       // 0..7
      int kg = kc * 32 + kq * 4;              // global k of this float4
      const float* src = (kg < 128) ? (Wl + (size_t)wo * UF + kg)
                                    : (Wr + (size_t)wo * UF + (kg - 128));
      float4 w = *(const float4*)src;
      Ws[kq * 4 + 0][wo] = w.x;
      Ws[kq * 4 + 1][wo] = w.y;
      Ws[kq * 4 + 2][wo] = w.z;
      Ws[kq * 4 + 3][wo] = w.w;
    }
    __syncthreads();
#pragma unroll 4
    for (int kw = 0; kw < 8; ++kw) {
      int k = kc * 32 + kw * 4;
      float4 a0 = *(const float4*)&As[n0][k];
      float4 a1 = *(const float4*)&As[n0 + 1][k];
      float4 w0 = *(const float4*)&Ws[kw * 4 + 0][o0];
      float4 w1 = *(const float4*)&Ws[kw * 4 + 1][o0];
      float4 w2 = *(const float4*)&Ws[kw * 4 + 2][o0];
      float4 w3 = *(const float4*)&Ws[kw * 4 + 3][o0];
      acc[0][0] = fmaf(a0.x, w0.x, acc[0][0]); acc[0][1] = fmaf(a0.x, w0.y, acc[0][1]);
      acc[0][2] = fmaf(a0.x, w0.z, acc[0][2]); acc[0][3] = fmaf(a0.x, w0.w, acc[0][3]);
      acc[1][0] = fmaf(a1.x, w0.x, acc[1][0]); acc[1][1] = fmaf(a1.x, w0.y, acc[1][1]);
      acc[1][2] = fmaf(a1.x, w0.z, acc[1][2]); acc[1][3] = fmaf(a1.x, w0.w, acc[1][3]);
      acc[0][0] = fmaf(a0.y, w1.x, acc[0][0]); acc[0][1] = fmaf(a0.y, w1.y, acc[0][1]);
      acc[0][2] = fmaf(a0.y, w1.z, acc[0][2]); acc[0][3] = fmaf(a0.y, w1.w, acc[0][3]);
      acc[1][0] = fmaf(a1.y, w1.x, acc[1][0]); acc[1][1] = fmaf(a1.y, w1.y, acc[1][1]);
      acc[1][2] = fmaf(a1.y, w1.z, acc[1][2]); acc[1][3] = fmaf(a1.y, w1.w, acc[1][3]);
      acc[0][0] = fmaf(a0.z, w2.x, acc[0][0]); acc[0][1] = fmaf(a0.z, w2.y, acc[0][1]);
      acc[0][2] = fmaf(a0.z, w2.z, acc[0][2]); acc[0][3] = fmaf(a0.z, w2.w, acc[0][3]);
      acc[1][0] = fmaf(a1.z, w2.x, acc[1][0]); acc[1][1] = fmaf(a1.z, w2.y, acc[1][1]);
      acc[1][2] = fmaf(a1.z, w2.z, acc[1][2]); acc[1][3] = fmaf(a1.z, w2.w, acc[1][3]);
      acc[0][0] = fmaf(a0.w, w3.x, acc[0][0]); acc[0][1] = fmaf(a0.w, w3.y, acc[0][1]);
      acc[0][2] = fmaf(a0.w, w3.z, acc[0][2]); acc[0][3] = fmaf(a0.w, w3.w, acc[0][3]);
      acc[1][0] = fmaf(a1.w, w3.x, acc[1][0]); acc[1][1] = fmaf(a1.w, w3.y, acc[1][1]);
      acc[1][2] = fmaf(a1.w, w3.z, acc[1][2]); acc[1][3] = fmaf(a1.w, w3.w, acc[1][3]);
    }
  }
#pragma unroll
  for (int i = 0; i < 2; ++i) {
    float4 r;
    r.x = acc[i][0] + bl[o0 + 0];
    r.y = acc[i][1] + bl[o0 + 1];
    r.z = acc[i][2] + bl[o0 + 2];
    r.w = acc[i][3] + bl[o0 + 3];
    if (TANH) { r.x = tanhf(r.x); r.y = tanhf(r.y); r.z = tanhf(r.z); r.w = tanhf(r.w); }
    *(float4*)(out + (size_t)(base + n0 + i) * UF + o0) = r;
  }
}

// ---------- fused actor+critic heads, same LDS-staged structure (KC=16) ----------
__global__ __launch_bounds__(256) void k_heads(
    const float* __restrict__ agg, const float* __restrict__ in,
    const float* __restrict__ Wa_l, const float* __restrict__ ba_l,
    const float* __restrict__ Wa_r,
    const float* __restrict__ Wcr_l, const float* __restrict__ bcr_l,
    const float* __restrict__ Wcr_r,
    const float* __restrict__ Wfa, const float* __restrict__ Wfc,
    float* __restrict__ a1, float* __restrict__ a2, float* __restrict__ cp) {
  __shared__ float As[16][260];
  __shared__ float WsA[16][132];
  __shared__ float WsC[16][132];
  __shared__ float red[3][16][33];
  const int t = threadIdx.x;
  const int base = blockIdx.x * 16;

#pragma unroll
  for (int r = 0; r < 4; ++r) {
    int idx = t + 256 * r;
    int row = idx >> 6;
    int k = (idx & 63) * 4;
    const float* src = (k < 128) ? (agg + (size_t)(base + row) * UF + k)
                                 : (in  + (size_t)(base + row) * UF + (k - 128));
    *(float4*)&As[row][k] = *(const float4*)src;
  }

  const int og = t & 31;
  const int o0 = og * 4;
  const int n0 = (t >> 5) * 2;
  const int wo = t & 127;
  const int kqb = (t >> 7) * 2;    // which 2 of the 4 float4-groups (KC=16)
  float accA[2][4] = {};
  float accC[2][4] = {};

  for (int kc = 0; kc < 16; ++kc) {
    __syncthreads();
#pragma unroll
    for (int q = 0; q < 2; ++q) {
      int kq = kqb + q;                       // 0..3
      int kg = kc * 16 + kq * 4;
      const float* sA = (kg < 128) ? (Wa_l  + (size_t)wo * UF + kg)
                                   : (Wa_r  + (size_t)wo * UF + (kg - 128));
      const float* sC = (kg < 128) ? (Wcr_l + (size_t)wo * UF + kg)
                                   : (Wcr_r + (size_t)wo * UF + (kg - 128));
      float4 wa = *(const float4*)sA;
      float4 wc = *(const float4*)sC;
      WsA[kq*4+0][wo] = wa.x; WsA[kq*4+1][wo] = wa.y;
      WsA[kq*4+2][wo] = wa.z; WsA[kq*4+3][wo] = wa.w;
      WsC[kq*4+0][wo] = wc.x; WsC[kq*4+1][wo] = wc.y;
      WsC[kq*4+2][wo] = wc.z; WsC[kq*4+3][wo] = wc.w;
    }
    __syncthreads();
#pragma unroll 2
    for (int kw = 0; kw < 4; ++kw) {
      int k = kc * 16 + kw * 4;
      float4 a0 = *(const float4*)&As[n0][k];
      float4 a1v = *(const float4*)&As[n0 + 1][k];
      const float* pa = &As[n0][0];  (void)pa;
#pragma unroll
      for (int j = 0; j < 4; ++j) {
        float4 wa = *(const float4*)&WsA[kw * 4 + j][o0];
        float4 wc = *(const float4*)&WsC[kw * 4 + j][o0];
        float e0 = (j == 0) ? a0.x : (j == 1) ? a0.y : (j == 2) ? a0.z : a0.w;
        float e1 = (j == 0) ? a1v.x : (j == 1) ? a1v.y : (j == 2) ? a1v.z : a1v.w;
        accA[0][0] = fmaf(e0, wa.x, accA[0][0]); accA[0][1] = fmaf(e0, wa.y, accA[0][1]);
        accA[0][2] = fmaf(e0, wa.z, accA[0][2]); accA[0][3] = fmaf(e0, wa.w, accA[0][3]);
        accA[1][0] = fmaf(e1, wa.x, accA[1][0]); accA[1][1] = fmaf(e1, wa.y, accA[1][1]);
        accA[1][2] = fmaf(e1, wa.z, accA[1][2]); accA[1][3] = fmaf(e1, wa.w, accA[1][3]);
        accC[0][0] = fmaf(e0, wc.x, accC[0][0]); accC[0][1] = fmaf(e0, wc.y, accC[0][1]);
        accC[0][2] = fmaf(e0, wc.z, accC[0][2]); accC[0][3] = fmaf(e0, wc.w, accC[0][3]);
        accC[1][0] = fmaf(e1, wc.x, accC[1][0]); accC[1][1] = fmaf(e1, wc.y, accC[1][1]);
        accC[1][2] = fmaf(e1, wc.z, accC[1][2]); accC[1][3] = fmaf(e1, wc.w, accC[1][3]);
      }
    }
  }
  // biases + project to a1/a2/cp partials
#pragma unroll
  for (int i = 0; i < 2; ++i) {
    float pa1 = 0.f, pa2 = 0.f, pc = 0.f;
#pragma unroll
    for (int j = 0; j < 4; ++j) {
      float xa = accA[i][j] + ba_l[o0 + j];
      float xc = accC[i][j] + bcr_l[o0 + j];
      pa1 = fmaf(xa, Wfa[o0 + j], pa1);
      pa2 = fmaf(xa, Wfa[UF + o0 + j], pa2);
      pc  = fmaf(xc, Wfc[o0 + j], pc);
    }
    red[0][n0 + i][og] = pa1;
    red[1][n0 + i][og] = pa2;
    red[2][n0 + i][og] = pc;
  }
  __syncthreads();
  if (t < 48) {
    int q = t >> 4, n = t & 15;
    float s = 0.f;
#pragma unroll
    for (int j = 0; j < 32; ++j) s += red[q][n][j];
    float* dst = (q == 0) ? a1 : (q == 1) ? a2 : cp;
    dst[base + n] = s;
  }
}

// ---------- global reductions: LSE constant + critic scalar ----------
__global__ __launch_bounds__(1024) void k_reduce(
    const float* __restrict__ a1, const float* __restrict__ a2,
    const float* __restrict__ cp, const float* __restrict__ bfc,
    float* __restrict__ consts, float* __restrict__ outc) {
  __shared__ float sm[1024];
  const int t = threadIdx.x;
  float x0 = a1[t*4], x1 = a1[t*4+1], x2 = a1[t*4+2], x3 = a1[t*4+3];
  float y0 = a2[t*4], y1 = a2[t*4+1], y2 = a2[t*4+2], y3 = a2[t*4+3];
  float c0 = cp[t*4], c1 = cp[t*4+1], c2 = cp[t*4+2], c3 = cp[t*4+3];

  sm[t] = fmaxf(fmaxf(x0, x1), fmaxf(x2, x3));
  __syncthreads();
  for (int off = 512; off > 0; off >>= 1) { if (t < off) sm[t] = fmaxf(sm[t], sm[t+off]); __syncthreads(); }
  float m1 = sm[0]; __syncthreads();

  sm[t] = fmaxf(fmaxf(y0, y1), fmaxf(y2, y3));
  __syncthreads();
  for (int off = 512; off > 0; off >>= 1) { if (t < off) sm[t] = fmaxf(sm[t], sm[t+off]); __syncthreads(); }
  float m2 = sm[0]; __syncthreads();

  sm[t] = expf(x0-m1) + expf(x1-m1) + expf(x2-m1) + expf(x3-m1);
  __syncthreads();
  for (int off = 512; off > 0; off >>= 1) { if (t < off) sm[t] += sm[t+off]; __syncthreads(); }
  float s1 = sm[0]; __syncthreads();

  sm[t] = expf(y0-m2) + expf(y1-m2) + expf(y2-m2) + expf(y3-m2);
  __syncthreads();
  for (int off = 512; off > 0; off >>= 1) { if (t < off) sm[t] += sm[t+off]; __syncthreads(); }
  float s2 = sm[0]; __syncthreads();

  sm[t] = c0 + c1 + c2 + c3;
  __syncthreads();
  for (int off = 512; off > 0; off >>= 1) { if (t < off) sm[t] += sm[t+off]; __syncthreads(); }
  float sc = sm[0];

  if (t == 0) {
    consts[0] = -(m1 + m2 + logf(s1) + logf(s2));
    outc[0] = tanhf(sc * (1.0f / (float)NN) + bfc[0]);
  }
}

// ---------- N^2 output write ----------
__global__ __launch_bounds__(256) void k_write(
    const float* __restrict__ a1, const float* __restrict__ a2,
    const float* __restrict__ consts, float* __restrict__ out) {
  int gid = blockIdx.x * 256 + threadIdx.x;        // one float4 per thread
  int row = gid >> 10;                             // 1024 float4 per row
  int c = (gid & 1023) * 4;
  float C = consts[0] + a1[row];
  float4 v = *(const float4*)(a2 + c);
  float4 r; r.x = v.x + C; r.y = v.y + C; r.z = v.z + C; r.w = v.w + C;
  *(float4*)(out + (size_t)gid * 4) = r;
}

extern "C" void kernel_launch(void* const* d_in, const int* in_sizes, int n_in,
                              void* d_out, int out_size, void* d_ws, size_t ws_size,
                              hipStream_t stream) {
  const float* x     = (const float*)d_in[0];
  const void*  ei    = d_in[1];
  const float* Wf_l  = (const float*)d_in[3];
  const float* bf_l  = (const float*)d_in[4];
  const float* Wf_r  = (const float*)d_in[5];
  const float* Wcm_l = (const float*)d_in[6];
  const float* bcm_l = (const float*)d_in[7];
  const float* Wcm_r = (const float*)d_in[8];
  const float* Wa_l  = (const float*)d_in[9];
  const float* ba_l  = (const float*)d_in[10];
  const float* Wa_r  = (const float*)d_in[11];
  const float* Wcr_l = (const float*)d_in[12];
  const float* bcr_l = (const float*)d_in[13];
  const float* Wcr_r = (const float*)d_in[14];
  const float* Wfa   = (const float*)d_in[15];
  const float* Wfc   = (const float*)d_in[17];
  const float* bfc   = (const float*)d_in[18];
  float* out = (float*)d_out;

  char* b = (char*)d_ws;
  size_t off = 0;
  int* flag = (int*)(b + off); off += 256;
  float* consts = (float*)(b + off); off += 256;
  int* deg = (int*)(b + off); off += (size_t)NN * 4;
  int* rowstart = (int*)(b + off); off += (size_t)(NN + 64) * 4;
  int* cursor = (int*)(b + off); off += (size_t)NN * 4;
  int* csr = (int*)(b + off); off += (size_t)NE * 4;
  float* a1 = (float*)(b + off); off += (size_t)NN * 4;
  float* a2 = (float*)(b + off); off += (size_t)NN * 4;
  float* cp = (float*)(b + off); off += (size_t)NN * 4;
  float* agg = (float*)(b + off); off += (size_t)NN * UF * 4;
  float* h1 = (float*)(b + off); off += (size_t)NN * UF * 4;
  float* h2 = (float*)(b + off); off += (size_t)NN * UF * 4;
  if (ws_size < off) return;

  k_init<<<16, 256, 0, stream>>>(flag, deg);
  k_detect<<<NE / 256, 256, 0, stream>>>((const long long*)ei, flag);
  k_count<<<NE / 256, 256, 0, stream>>>(ei, flag, deg);
  k_scan<<<1, 1024, 0, stream>>>(deg, rowstart, cursor);
  k_scatter<<<NE / 256, 256, 0, stream>>>(ei, flag, cursor, csr);

  k_aggregate<<<NN / 4, 256, 0, stream>>>(x, rowstart, csr, agg);
  k_layer<true><<<NN / 16, 256, 0, stream>>>(agg, x, Wf_l, bf_l, Wf_r, h1);
  k_aggregate<<<NN / 4, 256, 0, stream>>>(h1, rowstart, csr, agg);
  k_layer<true><<<NN / 16, 256, 0, stream>>>(agg, h1, Wcm_l, bcm_l, Wcm_r, h2);
  k_aggregate<<<NN / 4, 256, 0, stream>>>(h2, rowstart, csr, agg);
  k_heads<<<NN / 16, 256, 0, stream>>>(agg, h2, Wa_l, ba_l, Wa_r,
                                       Wcr_l, bcr_l, Wcr_r, Wfa, Wfc, a1, a2, cp);
  k_reduce<<<1, 1024, 0, stream>>>(a1, a2, cp, bfc, consts, out + (size_t)NN * NN);
  k_write<<<(NN * NN) / 1024, 256, 0, stream>>>(a1, a2, consts, out);
}